// Round 12
// baseline (241.046 us; speedup 1.0000x reference)
//
#include <hip/hip_runtime.h>

// ---------------------------------------------------------------------------
// RelativeStructureAttention (Music-Transformer style) on MI355X / gfx950.
//   b=2, n=1024, dim=1024, HEADS=16, d_h=64. Inputs fp32 (+int32 idx), out fp32.
// Round 21: r11 (best-of assembly, 227.2us; attn 60.8) + VARIABLE j-split:
//   ceil(nj/4)-way per it (4-way for it>=12, 3-way 8..11, 2-way 4..7, 1-way
//   <=3). Max piece = 4 tiles (halves the longest serial chain) with only
//   +25% prologue count (r4's uniform 4-way paid +100% and lost). Combine is
//   the 4-way guarded merge; prep writes MLp sentinels for unlaunched slots.
// Pipeline (5 launches):
//   0) prep            cast / pack_idx / build_tpad / MLp sentinels
//   1) gemm<2,128,64>  x@Wqkv^T -> QKVh (bf16 head-major, V^T), grid 768
//   2) attn            variable j-split (grid 16x40x2), partials to ws
//   3) combine         4-way guarded merge -> Ob (bf16)
//   4) gemm<1,64,64>   Ob@Wo^T -> d_out (fp32), grid 512 (2/CU)
// Workspace (64 MB): 0-8 O3 (over x_bf/Wq/Wk, dead post-QKV-gemm) | 10-12
//   Wo_bf | 12-13 Er+Tpad | 13-25 QKVh | 25-33 O2 | 33-37 Ob | 37-38 MLp |
//   39-47 Pidx | 48-56 O0 | 56-64 O1
// ---------------------------------------------------------------------------

using bf16x8 = __attribute__((ext_vector_type(8))) short;
using f32x4  = __attribute__((ext_vector_type(4))) float;

__device__ __forceinline__ float bf2f(unsigned short u) {
  unsigned x = ((unsigned)u) << 16;
  float f;
  __builtin_memcpy(&f, &x, 4);
  return f;
}
__device__ __forceinline__ unsigned short f2bf(float f) {
  unsigned x;
  __builtin_memcpy(&x, &f, 4);
  unsigned r = (x + 0x7FFFu + ((x >> 16) & 1u)) >> 16;  // round-nearest-even
  return (unsigned short)r;
}
__device__ __forceinline__ int f2i(float f) { int i; __builtin_memcpy(&i, &f, 4); return i; }
__device__ __forceinline__ float i2f(int i) { float f; __builtin_memcpy(&f, &i, 4); return f; }

union B8 { bf16x8 v; unsigned short u[8]; };

// ---------------------------------------------------------------------------
// prep: blocks 0..1023 cast six fp32 tensors -> bf16; 1024..2047 pack idx;
//       2048 builds Tpad; 2049..2052 write MLp sentinels (m=-3e38, l=0).
// ---------------------------------------------------------------------------
__global__ __launch_bounds__(256) void prep(
    const float* __restrict__ x,  const float* __restrict__ Wq,
    const float* __restrict__ Wk, const float* __restrict__ Wv,
    const float* __restrict__ Wo, const float* __restrict__ Er,
    const int* __restrict__ rb, const int* __restrict__ rp,
    const int* __restrict__ ro, const int* __restrict__ rs,
    const float* __restrict__ Tb, const float* __restrict__ Tp,
    const float* __restrict__ To, const float* __restrict__ Ts,
    unsigned short* __restrict__ x_bf, unsigned short* __restrict__ Wqkv,
    unsigned short* __restrict__ Wo_bf, unsigned short* __restrict__ Er_bf,
    unsigned* __restrict__ Pidx, unsigned short* __restrict__ Tpad,
    float* __restrict__ MLp)
{
  const int bid = blockIdx.x;
  const int tid = threadIdx.x;
  if (bid < 1024) {
    const int total = 1589248;  // 6,356,992 floats / 4
    for (int i = bid * 256 + tid; i < total; i += 1024 * 256) {
      const float4* s4;
      ushort4* d4;
      if (i < 524288)       { s4 = (const float4*)x  + i;           d4 = (ushort4*)x_bf  + i; }
      else if (i < 786432)  { s4 = (const float4*)Wq + (i-524288);  d4 = (ushort4*)Wqkv  + (i-524288); }
      else if (i < 1048576) { s4 = (const float4*)Wk + (i-786432);  d4 = (ushort4*)Wqkv  + (i-786432) + 262144; }
      else if (i < 1310720) { s4 = (const float4*)Wv + (i-1048576); d4 = (ushort4*)Wqkv  + (i-1048576) + 524288; }
      else if (i < 1572864) { s4 = (const float4*)Wo + (i-1310720); d4 = (ushort4*)Wo_bf + (i-1310720); }
      else                  { s4 = (const float4*)Er + (i-1572864); d4 = (ushort4*)Er_bf + (i-1572864); }
      const float4 v = *s4;
      ushort4 o;
      o.x = f2bf(v.x); o.y = f2bf(v.y); o.z = f2bf(v.z); o.w = f2bf(v.w);
      *d4 = o;
    }
  } else if (bid < 2048) {
    for (int i = (bid - 1024) * 256 + tid; i < 524288; i += 1024 * 256) {
      const int4 a = ((const int4*)rb)[i];
      const int4 b = ((const int4*)rp)[i];
      const int4 c = ((const int4*)ro)[i];
      const int4 d = ((const int4*)rs)[i];
      uint4 r;
      r.x = (unsigned)(a.x | (17+b.x)<<5 | (113+c.x)<<12 | (138+d.x)<<20);
      r.y = (unsigned)(a.y | (17+b.y)<<5 | (113+c.y)<<12 | (138+d.y)<<20);
      r.z = (unsigned)(a.z | (17+b.z)<<5 | (113+c.z)<<12 | (138+d.z)<<20);
      r.w = (unsigned)(a.w | (17+b.w)<<5 | (113+c.w)<<12 | (138+d.w)<<20);
      ((uint4*)Pidx)[i] = r;
    }
  } else if (bid == 2048) {
    // padded structure table: s [0..15]=bar,16=0,[17..111]=pos,112=0,
    // [113..136]=oct,137=0,[138..149]=sem,150..159=0. UNSCALED (qf has 1/8).
    for (int t = tid; t < 10240; t += 256) {
      const int s = t >> 6, d = t & 63;
      float v = 0.f;
      if (s < 16)       v = Tb[s * 64 + d];
      else if (s == 16) v = 0.f;
      else if (s < 112) v = Tp[(s - 17) * 64 + d];
      else if (s < 113) v = 0.f;
      else if (s < 137) v = To[(s - 113) * 64 + d];
      else if (s < 138) v = 0.f;
      else if (s < 150) v = Ts[(s - 138) * 64 + d];
      Tpad[t] = f2bf(v);
    }
  } else {
    // MLp sentinels: 4 pieces x 512 idx x 128 floats = 262144 floats.
    const int base = (bid - 2049) * 65536;
    for (int i = base + tid; i < base + 65536; i += 256)
      MLp[i] = ((i & 127) < 64) ? -3e38f : 0.f;
  }
}

// ---------------------------------------------------------------------------
// m97-style GEMM, block tile BM x BN, BK=32. MODE 1: f32 row-major out;
// MODE 2: bf16 QKV head-major — Q,K scalar scatter [i][d]; V TRANSPOSED
// [d][i] via packed ushort4 stores.
// ---------------------------------------------------------------------------
__device__ __forceinline__ void ld_lds16(const unsigned short* g, unsigned short* l) {
  __builtin_amdgcn_global_load_lds(
      (const __attribute__((address_space(1))) unsigned int*)g,
      (__attribute__((address_space(3))) unsigned int*)l, 16, 0, 0);
}

template <int MODE, int BM, int BN>
__global__ __launch_bounds__(256) void gemm_t(const unsigned short* __restrict__ A,
                                              const unsigned short* __restrict__ B,
                                              void* __restrict__ Cv,
                                              int M, int N, int K)
{
  constexpr int MT = BM / 32;
  constexpr int NT = BN / 32;
  __shared__ __align__(16) unsigned short Atile[BM * 32];
  __shared__ __align__(16) unsigned short Btile[BN * 32];
  const int tid = threadIdx.x;
  const int w = tid >> 6, lane = tid & 63;
  const int c15 = lane & 15, q = lane >> 4;
  const int wr = w >> 1, wc = w & 1;
  const int n0 = blockIdx.x * BN, m0 = blockIdx.y * BM;

  const unsigned short* ag = A + (size_t)(m0 + (tid >> 2)) * K + (tid & 3) * 8;
  const unsigned short* bg = B + (size_t)(n0 + (tid >> 2)) * K + (tid & 3) * 8;
  unsigned short* al = &Atile[tid * 8];
  unsigned short* bl = &Btile[tid * 8];
  const size_t half = (size_t)64 * K;

  f32x4 acc[MT][NT];
  #pragma unroll
  for (int mt = 0; mt < MT; mt++)
    #pragma unroll
    for (int nt = 0; nt < NT; nt++) { acc[mt][nt][0]=0.f; acc[mt][nt][1]=0.f; acc[mt][nt][2]=0.f; acc[mt][nt][3]=0.f; }

  for (int k0 = 0; k0 < K; k0 += 32) {
    __syncthreads();
    ld_lds16(ag + k0, al);
    if constexpr (BM == 128) ld_lds16(ag + half + k0, al + 2048);
    ld_lds16(bg + k0, bl);
    if constexpr (BN == 128) ld_lds16(bg + half + k0, bl + 2048);
    __syncthreads();

    bf16x8 af[MT], bfr[NT];
    #pragma unroll
    for (int mt = 0; mt < MT; mt++)
      af[mt] = *(const bf16x8*)&Atile[(wr * (BM / 2) + mt * 16 + c15) * 32 + q * 8];
    #pragma unroll
    for (int nt = 0; nt < NT; nt++)
      bfr[nt] = *(const bf16x8*)&Btile[(wc * (BN / 2) + nt * 16 + c15) * 32 + q * 8];
    #pragma unroll
    for (int mt = 0; mt < MT; mt++)
      #pragma unroll
      for (int nt = 0; nt < NT; nt++)
        acc[mt][nt] = __builtin_amdgcn_mfma_f32_16x16x32_bf16(af[mt], bfr[nt], acc[mt][nt], 0, 0, 0);
  }

  #pragma unroll
  for (int mt = 0; mt < MT; mt++)
    #pragma unroll
    for (int nt = 0; nt < NT; nt++) {
      const int mb = m0 + wr * (BM / 2) + mt * 16 + q * 4;   // i base (r=0)
      const int n  = n0 + wc * (BN / 2) + nt * 16 + c15;
      if constexpr (MODE == 1) {
        #pragma unroll
        for (int r = 0; r < 4; r++)
          ((float*)Cv)[(size_t)(mb + r) * N + n] = acc[mt][nt][r];
      } else {
        const int which = n >> 10, hh = (n >> 6) & 15, d = n & 63;
        const int bb = mb >> 10, i = mb & 1023;
        unsigned short* base = (unsigned short*)Cv + (size_t)which * 2097152 +
                               (((size_t)(bb << 4) + hh) << 16);
        if (which == 2) {
          // V^T[d][i..i+3], one 8B store
          ushort4 o;
          o.x = f2bf(acc[mt][nt][0]); o.y = f2bf(acc[mt][nt][1]);
          o.z = f2bf(acc[mt][nt][2]); o.w = f2bf(acc[mt][nt][3]);
          *(ushort4*)(base + ((size_t)d << 10) + i) = o;
        } else {
          #pragma unroll
          for (int r = 0; r < 4; r++)
            base[((size_t)(i + r) << 6) + d] = f2bf(acc[mt][nt][r]);
        }
      }
    }
}

// ---------------------------------------------------------------------------
// Flash attention, VARIABLE j-split (r7/r11 tile body, unchanged).
// grid (h=16, y=40, b=2) = 1280 blocks; y -> (it, s, nsplit):
//   y  0..15: it = 15-(y>>2),     s = y&3       (4-way, its 12..15)
//   y 16..27: it = 11-(z/3),      s = z%3, z=y-16 (3-way, its 8..11)
//   y 28..35: it = 7-(z>>1),      s = z&1, z=y-28 (2-way, its 4..7)
//   y 36..39: it = 3-z,           s = 0,   z=y-36 (1-way, its 0..3)
// Max piece = 4 tiles; no empty pieces. LDS 53248 B -> 3 blocks/CU.
// Epilogue: UNNORMALIZED fp32 O -> piece buffer O{s}; (m,l) -> MLp slot.
// ---------------------------------------------------------------------------
__global__ __launch_bounds__(256) void attn_kernel(
    const unsigned short* __restrict__ QKVh,  // head-major: Q | K | V^T
    const unsigned short* __restrict__ Tpad,  // 160 x 64 bf16, unscaled
    const unsigned* __restrict__ Pidx,
    const unsigned short* __restrict__ Er,
    float* __restrict__ O0, float* __restrict__ O1,
    float* __restrict__ O2, float* __restrict__ O3,
    float* __restrict__ MLp)
{
  const int h  = blockIdx.x;
  const int bb = blockIdx.z;
  const int y  = blockIdx.y;

  int it, s, jlo, cnt;
  if (y < 16) {
    it = 15 - (y >> 2); s = y & 3;
    const int nj = it + 1, b = nj >> 2, r = nj & 3;
    cnt = b + (s < r); jlo = s * b + (s < r ? s : r);
  } else if (y < 28) {
    const int z = y - 16;
    it = 11 - z / 3; s = z % 3;
    const int nj = it + 1, b = nj / 3, r = nj % 3;
    cnt = b + (s < r); jlo = s * b + (s < r ? s : r);
  } else if (y < 36) {
    const int z = y - 28;
    it = 7 - (z >> 1); s = z & 1;
    const int nj = it + 1, b = nj >> 1, r = nj & 1;
    cnt = b + (s < r); jlo = s * b + (s < r ? s : r);
  } else {
    it = 3 - (y - 36); s = 0;
    cnt = it + 1; jlo = 0;
  }
  const int jhi = jlo + cnt;
  const int i0  = it << 6;
  const int idx = (bb << 8) | (it << 4) | h;   // [0,512)
  float* ml = MLp + (size_t)(s * 512 + idx) * 128;
  float* Op = (s == 0 ? O0 : s == 1 ? O1 : s == 2 ? O2 : O3) + (size_t)idx * 4096;

  const int tid = threadIdx.x;
  const int w = tid >> 6;
  const int lane = tid & 63;
  const int c15 = lane & 15;
  const int q = lane >> 4;
  const int rowq = q * 4;

  __shared__ __align__(16) unsigned short Klds[2][64 * 64];  // dbuf, lane-order
  __shared__ __align__(16) unsigned short Vt2[64 * 64];      // V^T, XOR-swizzled
  __shared__ __align__(16) unsigned short C2[4][16 * 72];    // per-wave P scratch
  __shared__ __align__(16) unsigned short qeh[64 * 152];     // QE rows (fp16), perm
  unsigned short* c2w = &C2[w][0];

  const unsigned short* qhb  = QKVh + (((size_t)(bb << 4) + h) << 16);
  const unsigned short* khb  = qhb + 2097152;
  const unsigned short* vhbT = qhb + 2 * 2097152;            // V^T [64][1024]

  // ---- prologue: async-stage K tile jlo into buf 0 ----
  {
    const unsigned short* kp = khb + ((size_t)jlo << 12);
    ld_lds16(kp + tid * 8,        &Klds[0][tid * 8]);
    ld_lds16(kp + 2048 + tid * 8, &Klds[0][2048 + tid * 8]);
  }

  // ---- Q fragments, pre-scaled by 1/sqrt(d)=1/8 ----
  bf16x8 qf[2];
  {
    const unsigned short* qp = qhb + ((size_t)(i0 + w * 16 + c15) << 6);
    #pragma unroll
    for (int kk = 0; kk < 2; kk++) {
      B8 t;
      t.v = *(const bf16x8*)(qp + kk * 32 + q * 8);
      #pragma unroll
      for (int e = 0; e < 8; e++) t.u[e] = f2bf(bf2f(t.u[e]) * 0.125f);
      qf[kk] = t.v;
    }
  }

  // ---- this wave's 16 QE rows via MFMA; store at PHYS row r*4+q ----
  #pragma unroll
  for (int st = 0; st < 10; st++) {
    const unsigned short* tp = Tpad + (size_t)(st * 16 + c15) * 64 + q * 8;
    bf16x8 t0 = *(const bf16x8*)tp;
    bf16x8 t1 = *(const bf16x8*)(tp + 32);
    f32x4 a; a[0]=0.f; a[1]=0.f; a[2]=0.f; a[3]=0.f;
    a = __builtin_amdgcn_mfma_f32_16x16x32_bf16(qf[0], t0, a, 0, 0, 0);
    a = __builtin_amdgcn_mfma_f32_16x16x32_bf16(qf[1], t1, a, 0, 0, 0);
    const int col = st * 16 + c15;
    if (col < 152) {
      #pragma unroll
      for (int r = 0; r < 4; r++) {
        const _Float16 hv = (_Float16)a[r];
        unsigned short hb;
        __builtin_memcpy(&hb, &hv, 2);
        qeh[(w * 16 + r * 4 + q) * 152 + col] = hb;  // phys row perm
      }
    }
  }

  // ---- loop-invariant shear lane indices (per r) ----
  int perm[4];
  bool shi[4];
  #pragma unroll
  for (int r = 0; r < 4; r++) {
    const int t = 15 - (rowq + r) + c15;   // in [0,30]
    perm[r] = ((lane & 48) | (t & 15)) << 2;
    shi[r] = t > 15;
  }

  f32x4 Oa[4];
  float mrow[4], lrow[4];
  #pragma unroll
  for (int dt = 0; dt < 4; dt++) { Oa[dt][0]=0.f; Oa[dt][1]=0.f; Oa[dt][2]=0.f; Oa[dt][3]=0.f; }
  #pragma unroll
  for (int r = 0; r < 4; r++) { mrow[r] = -3e38f; lrow[r] = 0.f; }

  const int iw = i0 + w * 16;
  const size_t idx0 = ((size_t)bb << 20) + ((size_t)(iw + rowq) << 10);

  // V^T DMA decomposition: thread t stages phys 16B at Vt2 + t*8 (+2048);
  // source pre-swizzled so read-side XOR lands on logical (row=d, col=j).
  const int vr  = tid >> 3;                 // local row 0..31 (d)
  const int vcb = (tid & 7) * 8;            // phys col (shorts)
  const int vcl = vcb ^ ((vr & 7) << 3);    // logical col (shorts)

  for (int jt = jlo; jt < jhi; jt++) {
    const int j0 = jt << 6;
    const int cur = (jt - jlo) & 1;

    __syncthreads();  // K[cur] DMA complete; all waves past prev PV

    // ================= issue vmem, consumption order =======================
    // (1) Er band (consumed first by sb MFMAs)
    bf16x8 er0[5], er1[5];
    {
      const int rbase = 960 - i0 + j0;
      #pragma unroll
      for (int t5 = 0; t5 < 5; t5++) {
        const int pt = 3 - w + t5;
        int row = rbase + pt * 16 + c15;
        row = row > 1023 ? 1023 : row;   // masked-region overrun clamp
        const unsigned short* ep = Er + ((size_t)row << 6) + q * 8;
        er0[t5] = *(const bf16x8*)ep;
        er1[t5] = *(const bf16x8*)(ep + 32);
      }
    }
    // (2) V^T tile DMA (consumed after bottom barrier by PV)
    ld_lds16(vhbT + (size_t)vr * 1024 + j0 + vcl,          &Vt2[tid * 8]);
    ld_lds16(vhbT + (size_t)(vr + 32) * 1024 + j0 + vcl,   &Vt2[2048 + tid * 8]);
    // (3) Pidx (consumed by the bias gathers)
    unsigned pv[4][4];
    #pragma unroll
    for (int nt = 0; nt < 4; nt++)
      #pragma unroll
      for (int r = 0; r < 4; r++)
        pv[nt][r] = Pidx[idx0 + ((size_t)r << 10) + j0 + nt * 16 + c15];

    // ---- QK^T from Klds[cur] (pure LDS+MFMA; covers the loads' latency) ----
    f32x4 S[4];
    #pragma unroll
    for (int nt = 0; nt < 4; nt++) {
      f32x4 a; a[0]=0.f; a[1]=0.f; a[2]=0.f; a[3]=0.f;
      bf16x8 k0 = *(const bf16x8*)&Klds[cur][(nt * 16 + c15) * 64 + q * 8];
      bf16x8 k1 = *(const bf16x8*)&Klds[cur][(nt * 16 + c15) * 64 + 32 + q * 8];
      a = __builtin_amdgcn_mfma_f32_16x16x32_bf16(qf[0], k0, a, 0, 0, 0);
      a = __builtin_amdgcn_mfma_f32_16x16x32_bf16(qf[1], k1, a, 0, 0, 0);
      S[nt] = a;
    }

    // ---- Er-band MFMAs from registers ----
    f32x4 sb[5];
    #pragma unroll
    for (int t5 = 0; t5 < 5; t5++) {
      f32x4 a; a[0]=0.f; a[1]=0.f; a[2]=0.f; a[3]=0.f;
      a = __builtin_amdgcn_mfma_f32_16x16x32_bf16(qf[0], er0[t5], a, 0, 0, 0);
      a = __builtin_amdgcn_mfma_f32_16x16x32_bf16(qf[1], er1[t5], a, 0, 0, 0);
      sb[t5] = a;
    }

    // ---- K prefetch DMA: issued AFTER all reg-load consumers kicked off ----
    if (jt + 1 < jhi) {
      const unsigned short* kn = khb + ((size_t)(jt + 1) << 12);
      ld_lds16(kn + tid * 8,        &Klds[cur ^ 1][tid * 8]);
      ld_lds16(kn + 2048 + tid * 8, &Klds[cur ^ 1][2048 + tid * 8]);
    }

    // ---- scores: + Srel (bpermute shear) + structure bias, causal ----
    #pragma unroll
    for (int nt = 0; nt < 4; nt++) {
      const int j = j0 + nt * 16 + c15;
      #pragma unroll
      for (int r = 0; r < 4; r++) {
        const int rb = (w * 16 + r * 4 + q) * 152;  // phys row perm
        const unsigned p = pv[nt][r];
        _Float16 q0, q1, q2, q3;
        __builtin_memcpy(&q0, &qeh[rb + (p & 31)], 2);
        __builtin_memcpy(&q1, &qeh[rb + ((p >> 5) & 127)], 2);
        __builtin_memcpy(&q2, &qeh[rb + ((p >> 12) & 255)], 2);
        __builtin_memcpy(&q3, &qeh[rb + (p >> 20)], 2);
        const float bias = (float)(q0 + q1) + (float)(q2 + q3);
        const int vlo = __builtin_amdgcn_ds_bpermute(perm[r], f2i(sb[nt][r]));
        const int vhi = __builtin_amdgcn_ds_bpermute(perm[r], f2i(sb[nt + 1][r]));
        const float srel = i2f(shi[r] ? vhi : vlo);
        float sc = S[nt][r] + srel + bias;
        if (jt == it && j > iw + rowq + r) sc = -3e38f;  // causal
        S[nt][r] = sc;
      }
    }

    // ---- online softmax ----
    float alpha[4];
    #pragma unroll
    for (int r = 0; r < 4; r++) {
      float v = fmaxf(fmaxf(S[0][r], S[1][r]), fmaxf(S[2][r], S[3][r]));
      v = fmaxf(v, __shfl_xor(v, 1));
      v = fmaxf(v, __shfl_xor(v, 2));
      v = fmaxf(v, __shfl_xor(v, 4));
      v = fmaxf(v, __shfl_xor(v, 8));
      const float mn = fmaxf(mrow[r], v);
      alpha[r] = __expf(mrow[r] - mn);
      mrow[r] = mn;
    }
    #pragma unroll
    for (int nt = 0; nt < 4; nt++)
      #pragma unroll
      for (int r = 0; r < 4; r++)
        S[nt][r] = __expf(S[nt][r] - mrow[r]);
    #pragma unroll
    for (int r = 0; r < 4; r++) {
      float ssum = S[0][r] + S[1][r] + S[2][r] + S[3][r];
      ssum += __shfl_xor(ssum, 1);
      ssum += __shfl_xor(ssum, 2);
      ssum += __shfl_xor(ssum, 4);
      ssum += __shfl_xor(ssum, 8);
      lrow[r] = lrow[r] * alpha[r] + ssum;
      #pragma unroll
      for (int dt = 0; dt < 4; dt++) Oa[dt][r] *= alpha[r];
    }

    // ---- bottom barrier: counted vmcnt (K-prefetch stays in flight) ----
    if (jt + 1 < jhi) asm volatile("s_waitcnt vmcnt(2) lgkmcnt(0)" ::: "memory");
    else              asm volatile("s_waitcnt vmcnt(0) lgkmcnt(0)" ::: "memory");
    __builtin_amdgcn_s_barrier();
    __builtin_amdgcn_sched_barrier(0);

    // ---- P round-trip (per-wave LDS, bf16, stride 72; b128 readback) ----
    #pragma unroll
    for (int nt = 0; nt < 4; nt++)
      #pragma unroll
      for (int r = 0; r < 4; r++)
        c2w[(rowq + r) * 72 + nt * 16 + c15] = f2bf(S[nt][r]);

    bf16x8 pf[2];
    #pragma unroll
    for (int kk = 0; kk < 2; kk++)
      pf[kk] = *(const bf16x8*)&c2w[c15 * 72 + kk * 32 + q * 8];

    // ---- O += P @ V  (Vt2 row = dt*16+c15, XOR col swizzle) ----
    #pragma unroll
    for (int dt = 0; dt < 4; dt++) {
      const unsigned short* vp = &Vt2[(dt * 16 + c15) * 64];
      const int x0 = (q * 8)      ^ ((c15 & 7) << 3);
      const int x1 = (32 + q * 8) ^ ((c15 & 7) << 3);
      bf16x8 vv0 = *(const bf16x8*)(vp + x0);
      bf16x8 vv1 = *(const bf16x8*)(vp + x1);
      Oa[dt] = __builtin_amdgcn_mfma_f32_16x16x32_bf16(pf[0], vv0, Oa[dt], 0, 0, 0);
      Oa[dt] = __builtin_amdgcn_mfma_f32_16x16x32_bf16(pf[1], vv1, Oa[dt], 0, 0, 0);
    }
  }

  // ---- epilogue: UNNORMALIZED partials -> Op (fp32) + m,l ----
  #pragma unroll
  for (int dt = 0; dt < 4; dt++)
    #pragma unroll
    for (int r = 0; r < 4; r++)
      Op[(w * 16 + rowq + r) * 64 + dt * 16 + c15] = Oa[dt][r];
  if (c15 == 0) {
    #pragma unroll
    for (int r = 0; r < 4; r++) {
      ml[w * 16 + rowq + r]      = mrow[r];
      ml[64 + w * 16 + rowq + r] = lrow[r];
    }
  }
}

// ---------------------------------------------------------------------------
// combine: guarded 4-way merge of j-pieces -> Ob (b, i, h*64+d) bf16.
// grid (16 h, 16 it, 2 b), 256 thr; thread = (row = tid>>2, 16-col chunk).
// Pieces with l==0 (sentinel / unlaunched) contribute 0, panels unread.
// ---------------------------------------------------------------------------
__global__ __launch_bounds__(256) void combine(
    const float* __restrict__ O0, const float* __restrict__ O1,
    const float* __restrict__ O2, const float* __restrict__ O3,
    const float* __restrict__ MLp, unsigned short* __restrict__ Ob)
{
  const int h = blockIdx.x, it = blockIdx.y, bb = blockIdx.z;
  const int idx = (bb << 8) | (it << 4) | h;
  const int tid = threadIdx.x;
  const int row = tid >> 2;
  const int c0 = (tid & 3) << 4;

  const float* Os[4] = {O0, O1, O2, O3};
  float ms[4], ls[4], m = -3e38f;
  #pragma unroll
  for (int s = 0; s < 4; s++) {
    ms[s] = MLp[(size_t)(s * 512 + idx) * 128 + row];
    ls[s] = MLp[(size_t)(s * 512 + idx) * 128 + 64 + row];
    m = fmaxf(m, ms[s]);
  }
  float a[4], den = 0.f;
  #pragma unroll
  for (int s = 0; s < 4; s++) {
    a[s] = ls[s] > 0.f ? __expf(ms[s] - m) : 0.f;
    den += ls[s] * a[s];
  }
  const float inv = 1.f / den;

  float acc[16];
  #pragma unroll
  for (int e = 0; e < 16; e++) acc[e] = 0.f;
  #pragma unroll
  for (int s = 0; s < 4; s++) {
    if (a[s] > 0.f) {
      const float* p = Os[s] + (size_t)idx * 4096 + row * 64 + c0;
      #pragma unroll
      for (int cc = 0; cc < 4; cc++) {
        const float4 xv = *(const float4*)(p + cc * 4);
        acc[cc * 4 + 0] += a[s] * xv.x;
        acc[cc * 4 + 1] += a[s] * xv.y;
        acc[cc * 4 + 2] += a[s] * xv.z;
        acc[cc * 4 + 3] += a[s] * xv.w;
      }
    }
  }

  unsigned short* ob = Ob + ((size_t)(bb << 10) + (it << 6) + row) * 1024 + (h << 6) + c0;
  #pragma unroll
  for (int cc = 0; cc < 4; cc++) {
    ushort4 o;
    o.x = f2bf(acc[cc * 4 + 0] * inv);
    o.y = f2bf(acc[cc * 4 + 1] * inv);
    o.z = f2bf(acc[cc * 4 + 2] * inv);
    o.w = f2bf(acc[cc * 4 + 3] * inv);
    *(ushort4*)(ob + cc * 4) = o;
  }
}

// ---------------------------------------------------------------------------
extern "C" void kernel_launch(void* const* d_in, const int* in_sizes, int n_in,
                              void* d_out, int out_size, void* d_ws, size_t ws_size,
                              hipStream_t stream)
{
  const float* x    = (const float*)d_in[0];
  const int*   rbar = (const int*)d_in[1];
  const int*   rpos = (const int*)d_in[2];
  const int*   roct = (const int*)d_in[3];
  const int*   rsem = (const int*)d_in[4];
  const float* Wq   = (const float*)d_in[5];
  const float* Wk   = (const float*)d_in[6];
  const float* Wv   = (const float*)d_in[7];
  const float* Wo   = (const float*)d_in[8];
  const float* Er   = (const float*)d_in[9];
  const float* Tb   = (const float*)d_in[10];
  const float* Tp   = (const float*)d_in[11];
  const float* To   = (const float*)d_in[12];
  const float* Ts   = (const float*)d_in[13];
  float* out = (float*)d_out;

  // workspace layout (64 MB; piece buffers in attn-time-dead regions)
  char* ws = (char*)d_ws;
  const size_t MB = 1u << 20;
  unsigned short* x_bf    = (unsigned short*)(ws);             //  0-4  (dead post-QKV gemm)
  unsigned short* Wqkv_bf = (unsigned short*)(ws + 4 * MB);    //  4-10 (dead post-QKV gemm)
  unsigned short* Wo_bf   = (unsigned short*)(ws + 10 * MB);   // 10-12
  unsigned short* Er_bf   = (unsigned short*)(ws + 12 * MB);   // 12-12.25
  unsigned short* Tpad    = (unsigned short*)(ws + 12 * MB + 256 * 1024);
  unsigned short* QKVh    = (unsigned short*)(ws + 13 * MB);   // 13-25
  float*          O2p     = (float*)(ws + 25 * MB);            // 25-33
  unsigned short* Ob      = (unsigned short*)(ws + 33 * MB);   // 33-37
  float*          MLp     = (float*)(ws + 37 * MB);            // 37-38
  unsigned*       Pidx    = (unsigned*)(ws + 39 * MB);         // 39-47
  float*          O0p     = (float*)(ws + 48 * MB);            // 48-56
  float*          O1p     = (float*)(ws + 56 * MB);            // 56-64
  float*          O3p     = (float*)(ws);                      //  0-8 (over x_bf/Wq/Wk)

  prep<<<2053, 256, 0, stream>>>(x, Wq, Wk, Wv, Wo, Er, rbar, rpos, roct, rsem,
                                 Tb, Tp, To, Ts,
                                 x_bf, Wqkv_bf, Wo_bf, Er_bf, Pidx, Tpad, MLp);

  gemm_t<2, 128, 64><<<dim3(48, 16), 256, 0, stream>>>(x_bf, Wqkv_bf, QKVh, 2048, 3072, 1024);
  attn_kernel<<<dim3(16, 40, 2), 256, 0, stream>>>(QKVh, Tpad, Pidx, Er_bf,
                                                   O0p, O1p, O2p, O3p, MLp);
  combine<<<dim3(16, 16, 2), 256, 0, stream>>>(O0p, O1p, O2p, O3p, MLp, Ob);
  gemm_t<1, 64, 64><<<dim3(16, 32), 256, 0, stream>>>(Ob, Wo_bf, out, 2048, 1024, 1024);
}

// Round 13
// 226.708 us; speedup vs baseline: 1.0632x; 1.0632x over previous
//
#include <hip/hip_runtime.h>

// ---------------------------------------------------------------------------
// RelativeStructureAttention (Music-Transformer style) on MI355X / gfx950.
//   b=2, n=1024, dim=1024, HEADS=16, d_h=64. Inputs fp32 (+int32 idx), out fp32.
// FINAL (r11 config, best measured 227.2us): best-of-each-component assembly.
//   - attn  = r7 body (60.8us reproduced): V^T LDS DMA with pre-swizzled
//     source, counted vmcnt(2) bottom barrier, 2-way j-split (empirical
//     optimum: 4-way variants cost +24% via prologue overhead), Pidx 16x b32.
//   - gemm MODE2 = r8 epilogue (Q/K scalar scatter; V^T[d][i] ushort4).
//   - prep  = classic linear Pidx pack (uint4 stores).
// Pipeline (5 launches):
//   0) prep            fused cast / pack_idx / build_tpad (Tpad UNSCALED)
//   1) gemm<2,128,64>  x@Wqkv^T -> QKVh (bf16 head-major, V^T), grid 768
//   2) attn            2-way j-split, partials (O,m,l) to ws
//   3) combine         2-way merge -> Ob (bf16)
//   4) gemm<1,64,64>   Ob@Wo^T -> d_out (fp32), grid 512 (2/CU)
// ---------------------------------------------------------------------------

using bf16x8 = __attribute__((ext_vector_type(8))) short;
using f32x4  = __attribute__((ext_vector_type(4))) float;

__device__ __forceinline__ float bf2f(unsigned short u) {
  unsigned x = ((unsigned)u) << 16;
  float f;
  __builtin_memcpy(&f, &x, 4);
  return f;
}
__device__ __forceinline__ unsigned short f2bf(float f) {
  unsigned x;
  __builtin_memcpy(&x, &f, 4);
  unsigned r = (x + 0x7FFFu + ((x >> 16) & 1u)) >> 16;  // round-nearest-even
  return (unsigned short)r;
}
__device__ __forceinline__ int f2i(float f) { int i; __builtin_memcpy(&i, &f, 4); return i; }
__device__ __forceinline__ float i2f(int i) { float f; __builtin_memcpy(&f, &i, 4); return f; }

union B8 { bf16x8 v; unsigned short u[8]; };

// ---------------------------------------------------------------------------
// prep: blocks 0..1023 cast six fp32 tensors -> bf16; 1024..2047 pack idx;
//       block 2048 builds the padded 160x64 structure table (UNSCALED).
// ---------------------------------------------------------------------------
__global__ __launch_bounds__(256) void prep(
    const float* __restrict__ x,  const float* __restrict__ Wq,
    const float* __restrict__ Wk, const float* __restrict__ Wv,
    const float* __restrict__ Wo, const float* __restrict__ Er,
    const int* __restrict__ rb, const int* __restrict__ rp,
    const int* __restrict__ ro, const int* __restrict__ rs,
    const float* __restrict__ Tb, const float* __restrict__ Tp,
    const float* __restrict__ To, const float* __restrict__ Ts,
    unsigned short* __restrict__ x_bf, unsigned short* __restrict__ Wqkv,
    unsigned short* __restrict__ Wo_bf, unsigned short* __restrict__ Er_bf,
    unsigned* __restrict__ Pidx, unsigned short* __restrict__ Tpad)
{
  const int bid = blockIdx.x;
  const int tid = threadIdx.x;
  if (bid < 1024) {
    const int total = 1589248;  // 6,356,992 floats / 4
    for (int i = bid * 256 + tid; i < total; i += 1024 * 256) {
      const float4* s4;
      ushort4* d4;
      if (i < 524288)       { s4 = (const float4*)x  + i;           d4 = (ushort4*)x_bf  + i; }
      else if (i < 786432)  { s4 = (const float4*)Wq + (i-524288);  d4 = (ushort4*)Wqkv  + (i-524288); }
      else if (i < 1048576) { s4 = (const float4*)Wk + (i-786432);  d4 = (ushort4*)Wqkv  + (i-786432) + 262144; }
      else if (i < 1310720) { s4 = (const float4*)Wv + (i-1048576); d4 = (ushort4*)Wqkv  + (i-1048576) + 524288; }
      else if (i < 1572864) { s4 = (const float4*)Wo + (i-1310720); d4 = (ushort4*)Wo_bf + (i-1310720); }
      else                  { s4 = (const float4*)Er + (i-1572864); d4 = (ushort4*)Er_bf + (i-1572864); }
      const float4 v = *s4;
      ushort4 o;
      o.x = f2bf(v.x); o.y = f2bf(v.y); o.z = f2bf(v.z); o.w = f2bf(v.w);
      *d4 = o;
    }
  } else if (bid < 2048) {
    for (int i = (bid - 1024) * 256 + tid; i < 524288; i += 1024 * 256) {
      const int4 a = ((const int4*)rb)[i];
      const int4 b = ((const int4*)rp)[i];
      const int4 c = ((const int4*)ro)[i];
      const int4 d = ((const int4*)rs)[i];
      uint4 r;
      r.x = (unsigned)(a.x | (17+b.x)<<5 | (113+c.x)<<12 | (138+d.x)<<20);
      r.y = (unsigned)(a.y | (17+b.y)<<5 | (113+c.y)<<12 | (138+d.y)<<20);
      r.z = (unsigned)(a.z | (17+b.z)<<5 | (113+c.z)<<12 | (138+d.z)<<20);
      r.w = (unsigned)(a.w | (17+b.w)<<5 | (113+c.w)<<12 | (138+d.w)<<20);
      ((uint4*)Pidx)[i] = r;
    }
  } else {
    // padded structure table: s [0..15]=bar,16=0,[17..111]=pos,112=0,
    // [113..136]=oct,137=0,[138..149]=sem,150..159=0. UNSCALED (qf has 1/8).
    for (int t = tid; t < 10240; t += 256) {
      const int s = t >> 6, d = t & 63;
      float v = 0.f;
      if (s < 16)       v = Tb[s * 64 + d];
      else if (s == 16) v = 0.f;
      else if (s < 112) v = Tp[(s - 17) * 64 + d];
      else if (s < 113) v = 0.f;
      else if (s < 137) v = To[(s - 113) * 64 + d];
      else if (s < 138) v = 0.f;
      else if (s < 150) v = Ts[(s - 138) * 64 + d];
      Tpad[t] = f2bf(v);
    }
  }
}

// ---------------------------------------------------------------------------
// m97-style GEMM, block tile BM x BN, BK=32. MODE 1: f32 row-major out;
// MODE 2: bf16 QKV head-major — Q,K scalar scatter [i][d]; V TRANSPOSED
// [d][i] via packed ushort4 stores.
// ---------------------------------------------------------------------------
__device__ __forceinline__ void ld_lds16(const unsigned short* g, unsigned short* l) {
  __builtin_amdgcn_global_load_lds(
      (const __attribute__((address_space(1))) unsigned int*)g,
      (__attribute__((address_space(3))) unsigned int*)l, 16, 0, 0);
}

template <int MODE, int BM, int BN>
__global__ __launch_bounds__(256) void gemm_t(const unsigned short* __restrict__ A,
                                              const unsigned short* __restrict__ B,
                                              void* __restrict__ Cv,
                                              int M, int N, int K)
{
  constexpr int MT = BM / 32;
  constexpr int NT = BN / 32;
  __shared__ __align__(16) unsigned short Atile[BM * 32];
  __shared__ __align__(16) unsigned short Btile[BN * 32];
  const int tid = threadIdx.x;
  const int w = tid >> 6, lane = tid & 63;
  const int c15 = lane & 15, q = lane >> 4;
  const int wr = w >> 1, wc = w & 1;
  const int n0 = blockIdx.x * BN, m0 = blockIdx.y * BM;

  const unsigned short* ag = A + (size_t)(m0 + (tid >> 2)) * K + (tid & 3) * 8;
  const unsigned short* bg = B + (size_t)(n0 + (tid >> 2)) * K + (tid & 3) * 8;
  unsigned short* al = &Atile[tid * 8];
  unsigned short* bl = &Btile[tid * 8];
  const size_t half = (size_t)64 * K;

  f32x4 acc[MT][NT];
  #pragma unroll
  for (int mt = 0; mt < MT; mt++)
    #pragma unroll
    for (int nt = 0; nt < NT; nt++) { acc[mt][nt][0]=0.f; acc[mt][nt][1]=0.f; acc[mt][nt][2]=0.f; acc[mt][nt][3]=0.f; }

  for (int k0 = 0; k0 < K; k0 += 32) {
    __syncthreads();
    ld_lds16(ag + k0, al);
    if constexpr (BM == 128) ld_lds16(ag + half + k0, al + 2048);
    ld_lds16(bg + k0, bl);
    if constexpr (BN == 128) ld_lds16(bg + half + k0, bl + 2048);
    __syncthreads();

    bf16x8 af[MT], bfr[NT];
    #pragma unroll
    for (int mt = 0; mt < MT; mt++)
      af[mt] = *(const bf16x8*)&Atile[(wr * (BM / 2) + mt * 16 + c15) * 32 + q * 8];
    #pragma unroll
    for (int nt = 0; nt < NT; nt++)
      bfr[nt] = *(const bf16x8*)&Btile[(wc * (BN / 2) + nt * 16 + c15) * 32 + q * 8];
    #pragma unroll
    for (int mt = 0; mt < MT; mt++)
      #pragma unroll
      for (int nt = 0; nt < NT; nt++)
        acc[mt][nt] = __builtin_amdgcn_mfma_f32_16x16x32_bf16(af[mt], bfr[nt], acc[mt][nt], 0, 0, 0);
  }

  #pragma unroll
  for (int mt = 0; mt < MT; mt++)
    #pragma unroll
    for (int nt = 0; nt < NT; nt++) {
      const int mb = m0 + wr * (BM / 2) + mt * 16 + q * 4;   // i base (r=0)
      const int n  = n0 + wc * (BN / 2) + nt * 16 + c15;
      if constexpr (MODE == 1) {
        #pragma unroll
        for (int r = 0; r < 4; r++)
          ((float*)Cv)[(size_t)(mb + r) * N + n] = acc[mt][nt][r];
      } else {
        const int which = n >> 10, hh = (n >> 6) & 15, d = n & 63;
        const int bb = mb >> 10, i = mb & 1023;
        unsigned short* base = (unsigned short*)Cv + (size_t)which * 2097152 +
                               (((size_t)(bb << 4) + hh) << 16);
        if (which == 2) {
          // V^T[d][i..i+3], one 8B store
          ushort4 o;
          o.x = f2bf(acc[mt][nt][0]); o.y = f2bf(acc[mt][nt][1]);
          o.z = f2bf(acc[mt][nt][2]); o.w = f2bf(acc[mt][nt][3]);
          *(ushort4*)(base + ((size_t)d << 10) + i) = o;
        } else {
          #pragma unroll
          for (int r = 0; r < 4; r++)
            base[((size_t)(i + r) << 6) + d] = f2bf(acc[mt][nt][r]);
        }
      }
    }
}

// ---------------------------------------------------------------------------
// Flash attention, 2-way j-split; V^T staged by DMA (r7 body = best measured).
// grid (h=16, y=32, b=2) = 1024 blocks. LDS 53248 B -> 3 blocks/CU.
// qeh row perm: logical row x=q*4+r stored at phys r*4+q (stride 152).
// Vt2: linear [64][64], logical (row=d, col=j) at byte row*128 +
//   (col*2 ^ ((row&7)<<4)); swizzle realized via pre-swizzled DMA source.
// Epilogue: UNNORMALIZED fp32 O + (m,l) partials; combine merges.
// ---------------------------------------------------------------------------
__global__ __launch_bounds__(256) void attn_kernel(
    const unsigned short* __restrict__ QKVh,  // head-major: Q | K | V^T
    const unsigned short* __restrict__ Tpad,  // 160 x 64 bf16, unscaled
    const unsigned* __restrict__ Pidx,
    const unsigned short* __restrict__ Er,
    float* __restrict__ Opart, float* __restrict__ MLp)
{
  const int h   = blockIdx.x;
  const int bb  = blockIdx.z;
  const int itv = blockIdx.y >> 1;
  const int s   = blockIdx.y & 1;
  const int it  = 15 - itv;            // longest-first dispatch
  const int i0  = it << 6;
  const int nj  = it + 1;
  const int njh = (nj + 1) >> 1;
  const int jlo = s ? njh : 0;
  const int jhi = s ? nj : njh;
  const int pblk = (((bb << 1) | s) << 8) | (it << 4) | h;

  const int tid = threadIdx.x;
  const int w = tid >> 6;
  const int lane = tid & 63;
  const int c15 = lane & 15;
  const int q = lane >> 4;
  const int rowq = q * 4;

  __shared__ __align__(16) unsigned short Klds[2][64 * 64];  // dbuf, lane-order
  __shared__ __align__(16) unsigned short Vt2[64 * 64];      // V^T, XOR-swizzled
  __shared__ __align__(16) unsigned short C2[4][16 * 72];    // per-wave P scratch
  __shared__ __align__(16) unsigned short qeh[64 * 152];     // QE rows (fp16), perm
  unsigned short* c2w = &C2[w][0];

  const unsigned short* qhb  = QKVh + (((size_t)(bb << 4) + h) << 16);
  const unsigned short* khb  = qhb + 2097152;
  const unsigned short* vhbT = qhb + 2 * 2097152;            // V^T [64][1024]

  // ---- prologue: async-stage K tile jlo into buf 0 ----
  if (jlo < jhi) {
    const unsigned short* kp = khb + ((size_t)jlo << 12);
    ld_lds16(kp + tid * 8,        &Klds[0][tid * 8]);
    ld_lds16(kp + 2048 + tid * 8, &Klds[0][2048 + tid * 8]);
  }

  // ---- Q fragments, pre-scaled by 1/sqrt(d)=1/8 ----
  bf16x8 qf[2];
  {
    const unsigned short* qp = qhb + ((size_t)(i0 + w * 16 + c15) << 6);
    #pragma unroll
    for (int kk = 0; kk < 2; kk++) {
      B8 t;
      t.v = *(const bf16x8*)(qp + kk * 32 + q * 8);
      #pragma unroll
      for (int e = 0; e < 8; e++) t.u[e] = f2bf(bf2f(t.u[e]) * 0.125f);
      qf[kk] = t.v;
    }
  }

  // ---- this wave's 16 QE rows via MFMA; store at PHYS row r*4+q ----
  #pragma unroll
  for (int st = 0; st < 10; st++) {
    const unsigned short* tp = Tpad + (size_t)(st * 16 + c15) * 64 + q * 8;
    bf16x8 t0 = *(const bf16x8*)tp;
    bf16x8 t1 = *(const bf16x8*)(tp + 32);
    f32x4 a; a[0]=0.f; a[1]=0.f; a[2]=0.f; a[3]=0.f;
    a = __builtin_amdgcn_mfma_f32_16x16x32_bf16(qf[0], t0, a, 0, 0, 0);
    a = __builtin_amdgcn_mfma_f32_16x16x32_bf16(qf[1], t1, a, 0, 0, 0);
    const int col = st * 16 + c15;
    if (col < 152) {
      #pragma unroll
      for (int r = 0; r < 4; r++) {
        const _Float16 hv = (_Float16)a[r];
        unsigned short hb;
        __builtin_memcpy(&hb, &hv, 2);
        qeh[(w * 16 + r * 4 + q) * 152 + col] = hb;  // phys row perm
      }
    }
  }

  // ---- loop-invariant shear lane indices (per r) ----
  int perm[4];
  bool shi[4];
  #pragma unroll
  for (int r = 0; r < 4; r++) {
    const int t = 15 - (rowq + r) + c15;   // in [0,30]
    perm[r] = ((lane & 48) | (t & 15)) << 2;
    shi[r] = t > 15;
  }

  f32x4 Oa[4];
  float mrow[4], lrow[4];
  #pragma unroll
  for (int dt = 0; dt < 4; dt++) { Oa[dt][0]=0.f; Oa[dt][1]=0.f; Oa[dt][2]=0.f; Oa[dt][3]=0.f; }
  #pragma unroll
  for (int r = 0; r < 4; r++) { mrow[r] = -3e38f; lrow[r] = 0.f; }

  const int iw = i0 + w * 16;
  const size_t idx0 = ((size_t)bb << 20) + ((size_t)(iw + rowq) << 10);

  // V^T DMA decomposition: thread t stages phys 16B at Vt2 + t*8 (+2048);
  // source pre-swizzled so read-side XOR lands on logical (row=d, col=j).
  const int vr  = tid >> 3;                 // local row 0..31 (d)
  const int vcb = (tid & 7) * 8;            // phys col (shorts)
  const int vcl = vcb ^ ((vr & 7) << 3);    // logical col (shorts)

  for (int jt = jlo; jt < jhi; jt++) {
    const int j0 = jt << 6;
    const int cur = (jt - jlo) & 1;

    __syncthreads();  // K[cur] DMA complete; all waves past prev PV

    // ================= issue vmem, consumption order =======================
    // (1) Er band (consumed first by sb MFMAs)
    bf16x8 er0[5], er1[5];
    {
      const int rbase = 960 - i0 + j0;
      #pragma unroll
      for (int t5 = 0; t5 < 5; t5++) {
        const int pt = 3 - w + t5;
        int row = rbase + pt * 16 + c15;
        row = row > 1023 ? 1023 : row;   // masked-region overrun clamp
        const unsigned short* ep = Er + ((size_t)row << 6) + q * 8;
        er0[t5] = *(const bf16x8*)ep;
        er1[t5] = *(const bf16x8*)(ep + 32);
      }
    }
    // (2) V^T tile DMA (consumed after bottom barrier by PV)
    ld_lds16(vhbT + (size_t)vr * 1024 + j0 + vcl,          &Vt2[tid * 8]);
    ld_lds16(vhbT + (size_t)(vr + 32) * 1024 + j0 + vcl,   &Vt2[2048 + tid * 8]);
    // (3) Pidx (consumed by the bias gathers)
    unsigned pv[4][4];
    #pragma unroll
    for (int nt = 0; nt < 4; nt++)
      #pragma unroll
      for (int r = 0; r < 4; r++)
        pv[nt][r] = Pidx[idx0 + ((size_t)r << 10) + j0 + nt * 16 + c15];

    // ---- QK^T from Klds[cur] (pure LDS+MFMA; covers the loads' latency) ----
    f32x4 S[4];
    #pragma unroll
    for (int nt = 0; nt < 4; nt++) {
      f32x4 a; a[0]=0.f; a[1]=0.f; a[2]=0.f; a[3]=0.f;
      bf16x8 k0 = *(const bf16x8*)&Klds[cur][(nt * 16 + c15) * 64 + q * 8];
      bf16x8 k1 = *(const bf16x8*)&Klds[cur][(nt * 16 + c15) * 64 + 32 + q * 8];
      a = __builtin_amdgcn_mfma_f32_16x16x32_bf16(qf[0], k0, a, 0, 0, 0);
      a = __builtin_amdgcn_mfma_f32_16x16x32_bf16(qf[1], k1, a, 0, 0, 0);
      S[nt] = a;
    }

    // ---- Er-band MFMAs from registers ----
    f32x4 sb[5];
    #pragma unroll
    for (int t5 = 0; t5 < 5; t5++) {
      f32x4 a; a[0]=0.f; a[1]=0.f; a[2]=0.f; a[3]=0.f;
      a = __builtin_amdgcn_mfma_f32_16x16x32_bf16(qf[0], er0[t5], a, 0, 0, 0);
      a = __builtin_amdgcn_mfma_f32_16x16x32_bf16(qf[1], er1[t5], a, 0, 0, 0);
      sb[t5] = a;
    }

    // ---- K prefetch DMA: issued AFTER all reg-load consumers kicked off ----
    if (jt + 1 < jhi) {
      const unsigned short* kn = khb + ((size_t)(jt + 1) << 12);
      ld_lds16(kn + tid * 8,        &Klds[cur ^ 1][tid * 8]);
      ld_lds16(kn + 2048 + tid * 8, &Klds[cur ^ 1][2048 + tid * 8]);
    }

    // ---- scores: + Srel (bpermute shear) + structure bias, causal ----
    #pragma unroll
    for (int nt = 0; nt < 4; nt++) {
      const int j = j0 + nt * 16 + c15;
      #pragma unroll
      for (int r = 0; r < 4; r++) {
        const int rb = (w * 16 + r * 4 + q) * 152;  // phys row perm
        const unsigned p = pv[nt][r];
        _Float16 q0, q1, q2, q3;
        __builtin_memcpy(&q0, &qeh[rb + (p & 31)], 2);
        __builtin_memcpy(&q1, &qeh[rb + ((p >> 5) & 127)], 2);
        __builtin_memcpy(&q2, &qeh[rb + ((p >> 12) & 255)], 2);
        __builtin_memcpy(&q3, &qeh[rb + (p >> 20)], 2);
        const float bias = (float)(q0 + q1) + (float)(q2 + q3);
        const int vlo = __builtin_amdgcn_ds_bpermute(perm[r], f2i(sb[nt][r]));
        const int vhi = __builtin_amdgcn_ds_bpermute(perm[r], f2i(sb[nt + 1][r]));
        const float srel = i2f(shi[r] ? vhi : vlo);
        float sc = S[nt][r] + srel + bias;
        if (jt == it && j > iw + rowq + r) sc = -3e38f;  // causal
        S[nt][r] = sc;
      }
    }

    // ---- online softmax ----
    float alpha[4];
    #pragma unroll
    for (int r = 0; r < 4; r++) {
      float v = fmaxf(fmaxf(S[0][r], S[1][r]), fmaxf(S[2][r], S[3][r]));
      v = fmaxf(v, __shfl_xor(v, 1));
      v = fmaxf(v, __shfl_xor(v, 2));
      v = fmaxf(v, __shfl_xor(v, 4));
      v = fmaxf(v, __shfl_xor(v, 8));
      const float mn = fmaxf(mrow[r], v);
      alpha[r] = __expf(mrow[r] - mn);
      mrow[r] = mn;
    }
    #pragma unroll
    for (int nt = 0; nt < 4; nt++)
      #pragma unroll
      for (int r = 0; r < 4; r++)
        S[nt][r] = __expf(S[nt][r] - mrow[r]);
    #pragma unroll
    for (int r = 0; r < 4; r++) {
      float ssum = S[0][r] + S[1][r] + S[2][r] + S[3][r];
      ssum += __shfl_xor(ssum, 1);
      ssum += __shfl_xor(ssum, 2);
      ssum += __shfl_xor(ssum, 4);
      ssum += __shfl_xor(ssum, 8);
      lrow[r] = lrow[r] * alpha[r] + ssum;
      #pragma unroll
      for (int dt = 0; dt < 4; dt++) Oa[dt][r] *= alpha[r];
    }

    // ---- bottom barrier: counted vmcnt (K-prefetch stays in flight) ----
    if (jt + 1 < jhi) asm volatile("s_waitcnt vmcnt(2) lgkmcnt(0)" ::: "memory");
    else              asm volatile("s_waitcnt vmcnt(0) lgkmcnt(0)" ::: "memory");
    __builtin_amdgcn_s_barrier();
    __builtin_amdgcn_sched_barrier(0);

    // ---- P round-trip (per-wave LDS, bf16, stride 72; b128 readback) ----
    #pragma unroll
    for (int nt = 0; nt < 4; nt++)
      #pragma unroll
      for (int r = 0; r < 4; r++)
        c2w[(rowq + r) * 72 + nt * 16 + c15] = f2bf(S[nt][r]);

    bf16x8 pf[2];
    #pragma unroll
    for (int kk = 0; kk < 2; kk++)
      pf[kk] = *(const bf16x8*)&c2w[c15 * 72 + kk * 32 + q * 8];

    // ---- O += P @ V  (Vt2 row = dt*16+c15, XOR col swizzle) ----
    #pragma unroll
    for (int dt = 0; dt < 4; dt++) {
      const unsigned short* vp = &Vt2[(dt * 16 + c15) * 64];
      const int x0 = (q * 8)      ^ ((c15 & 7) << 3);
      const int x1 = (32 + q * 8) ^ ((c15 & 7) << 3);
      bf16x8 vv0 = *(const bf16x8*)(vp + x0);
      bf16x8 vv1 = *(const bf16x8*)(vp + x1);
      Oa[dt] = __builtin_amdgcn_mfma_f32_16x16x32_bf16(pf[0], vv0, Oa[dt], 0, 0, 0);
      Oa[dt] = __builtin_amdgcn_mfma_f32_16x16x32_bf16(pf[1], vv1, Oa[dt], 0, 0, 0);
    }
  }

  // ---- epilogue: UNNORMALIZED partials -> Opart (fp32) + m,l ----
  float* Op = Opart + (size_t)pblk * 4096;
  #pragma unroll
  for (int dt = 0; dt < 4; dt++)
    #pragma unroll
    for (int r = 0; r < 4; r++)
      Op[(w * 16 + rowq + r) * 64 + dt * 16 + c15] = Oa[dt][r];
  if (c15 == 0) {
    #pragma unroll
    for (int r = 0; r < 4; r++) {
      MLp[pblk * 128 + w * 16 + rowq + r]      = mrow[r];
      MLp[pblk * 128 + 64 + w * 16 + rowq + r] = lrow[r];
    }
  }
}

// ---------------------------------------------------------------------------
// combine: merge the two j-halves -> Ob (b, i, h*64+d) bf16.
// grid (16 h, 16 it, 2 b), 256 thr; thread = (row = tid>>2, 16-col chunk).
// ---------------------------------------------------------------------------
__global__ __launch_bounds__(256) void combine(
    const float* __restrict__ Opart, const float* __restrict__ MLp,
    unsigned short* __restrict__ Ob)
{
  const int h = blockIdx.x, it = blockIdx.y, bb = blockIdx.z;
  const int p0 = (((bb << 1) | 0) << 8) | (it << 4) | h;
  const int p1 = (((bb << 1) | 1) << 8) | (it << 4) | h;
  const int tid = threadIdx.x;
  const int row = tid >> 2;
  const int c0 = (tid & 3) << 4;

  const float m0 = MLp[p0 * 128 + row], l0 = MLp[p0 * 128 + 64 + row];
  const float m1 = MLp[p1 * 128 + row], l1 = MLp[p1 * 128 + 64 + row];
  const float m  = fmaxf(m0, m1);
  const float a0 = __expf(m0 - m), a1 = __expf(m1 - m);
  const float inv = 1.f / (l0 * a0 + l1 * a1);

  const float* q0 = Opart + (size_t)p0 * 4096 + row * 64 + c0;
  const float* q1 = Opart + (size_t)p1 * 4096 + row * 64 + c0;
  unsigned short* ob = Ob + ((size_t)(bb << 10) + (it << 6) + row) * 1024 + (h << 6) + c0;
  #pragma unroll
  for (int cc = 0; cc < 4; cc++) {
    const float4 x0 = *(const float4*)(q0 + cc * 4);
    const float4 x1 = *(const float4*)(q1 + cc * 4);
    ushort4 o;
    o.x = f2bf((x0.x * a0 + x1.x * a1) * inv);
    o.y = f2bf((x0.y * a0 + x1.y * a1) * inv);
    o.z = f2bf((x0.z * a0 + x1.z * a1) * inv);
    o.w = f2bf((x0.w * a0 + x1.w * a1) * inv);
    *(ushort4*)(ob + cc * 4) = o;
  }
}

// ---------------------------------------------------------------------------
extern "C" void kernel_launch(void* const* d_in, const int* in_sizes, int n_in,
                              void* d_out, int out_size, void* d_ws, size_t ws_size,
                              hipStream_t stream)
{
  const float* x    = (const float*)d_in[0];
  const int*   rbar = (const int*)d_in[1];
  const int*   rpos = (const int*)d_in[2];
  const int*   roct = (const int*)d_in[3];
  const int*   rsem = (const int*)d_in[4];
  const float* Wq   = (const float*)d_in[5];
  const float* Wk   = (const float*)d_in[6];
  const float* Wv   = (const float*)d_in[7];
  const float* Wo   = (const float*)d_in[8];
  const float* Er   = (const float*)d_in[9];
  const float* Tb   = (const float*)d_in[10];
  const float* Tp   = (const float*)d_in[11];
  const float* To   = (const float*)d_in[12];
  const float* Ts   = (const float*)d_in[13];
  float* out = (float*)d_out;

  // workspace layout (~64 MB, r12-proven map)
  char* ws = (char*)d_ws;
  const size_t MB = 1u << 20;
  unsigned short* x_bf    = (unsigned short*)(ws);             //  4 MB
  unsigned short* Wqkv_bf = (unsigned short*)(ws + 4 * MB);    //  6 MB
  unsigned short* Wo_bf   = (unsigned short*)(ws + 10 * MB);   //  2 MB
  unsigned short* Er_bf   = (unsigned short*)(ws + 12 * MB);   //  128 KB
  unsigned short* Tpad    = (unsigned short*)(ws + 12 * MB + 256 * 1024);  // 20 KB
  unsigned short* QKVh    = (unsigned short*)(ws + 13 * MB);   // 12 MB (head-major Q|K|V^T)
  unsigned short* Ob      = (unsigned short*)(ws + 25 * MB);   //  4 MB
  unsigned*       Pidx    = (unsigned*)(ws + 39 * MB);         //  8 MB
  float*          MLp     = (float*)(ws + 47 * MB);            //  512 KB
  float*          Opart   = (float*)(ws + 48 * MB);            //  16 MB

  prep<<<2049, 256, 0, stream>>>(x, Wq, Wk, Wv, Wo, Er, rbar, rpos, roct, rsem,
                                 Tb, Tp, To, Ts,
                                 x_bf, Wqkv_bf, Wo_bf, Er_bf, Pidx, Tpad);

  gemm_t<2, 128, 64><<<dim3(48, 16), 256, 0, stream>>>(x_bf, Wqkv_bf, QKVh, 2048, 3072, 1024);
  attn_kernel<<<dim3(16, 32, 2), 256, 0, stream>>>(QKVh, Tpad, Pidx, Er_bf, Opart, MLp);
  combine<<<dim3(16, 16, 2), 256, 0, stream>>>(Opart, MLp, Ob);
  gemm_t<1, 64, 64><<<dim3(16, 32), 256, 0, stream>>>(Ob, Wo_bf, out, 2048, 1024, 1024);
}